// Round 1
// baseline (7646.411 us; speedup 1.0000x reference)
//
#include <hip/hip_runtime.h>
#include <math.h>

#define L_ 37
#define K_ 8
#define HM_ 512
#define HS_ 128
#define HC_ 64
#define CONV_S 164   // like LDS row stride (floats): 16 left pad + 128 + 20 right pad; 2-way-conflict-friendly

// ---------- ws layout (bytes) ----------
static constexpr size_t OFF_PARAMS = 0;                                   // 74 f (scale,shift per l)
static constexpr size_t OFF_TAJ  = 1024;                                  // 128 int
static constexpr size_t OFF_TAW  = OFF_TAJ + 512;                         // 128*16 f
static constexpr size_t OFF_TBJ  = OFF_TAW + 128*16*4;                    // 128 int
static constexpr size_t OFF_TBW  = OFF_TBJ + 512;                         // 128*4 f
static constexpr size_t OFF_TCJ  = OFF_TBW + 128*4*4;                     // 512 int
static constexpr size_t OFF_TCW  = OFF_TCJ + 512*4;                       // 512*4 f
static constexpr size_t OFF_TMPA = ((OFF_TCW + 512*4*4 + 1023)/1024)*1024; // 74*128*512 f
static constexpr size_t OFF_HMRS = OFF_TMPA + (size_t)74*128*512*4;       // 74*128*128 f
static constexpr size_t OFF_PRIOR= OFF_HMRS + (size_t)74*128*128*4;       // 296*128*128 f
static constexpr size_t OFF_E128 = OFF_PRIOR + (size_t)296*128*128*4;     // 74*128*128 f

__device__ __forceinline__ float keys_cubic(float x) {
  // jax _fill_keys_cubic_kernel (a = -0.5)
  float out = ((1.5f * x - 2.5f) * x) * x + 1.f;
  if (x >= 1.f) out = ((-0.5f * x + 2.5f) * x - 4.f) * x + 2.f;
  if (x >= 2.f) out = 0.f;
  return out;
}
__device__ __forceinline__ float softplus_b(float x) {
  // softplus(5x)/5, stable form matching jax.nn.softplus = max(z,0)+log1p(exp(-|z|))
  float z = 5.f * x;
  return (fmaxf(z, 0.f) + log1pf(expf(-fabsf(z)))) * 0.2f;
}

// ---------------- BN stats per layer ----------------
__global__ void bn_stats_k(const float* __restrict__ heat, const float* __restrict__ gamma,
                           const float* __restrict__ beta, float* __restrict__ params) {
  int l = blockIdx.x, tid = threadIdx.x;
  const int NPL = HM_ * HM_;
  float s = 0.f, sq = 0.f;
  for (int b = 0; b < 2; ++b) {
    const float* p = heat + ((size_t)b * L_ + l) * NPL;
    for (int i = tid; i < NPL; i += 256) { float v = p[i]; s += v; sq += v * v; }
  }
  __shared__ float rs[256], rq[256];
  rs[tid] = s; rq[tid] = sq; __syncthreads();
  for (int o = 128; o > 0; o >>= 1) {
    if (tid < o) { rs[tid] += rs[tid + o]; rq[tid] += rq[tid + o]; }
    __syncthreads();
  }
  if (tid == 0) {
    float inv = 1.f / (2.f * NPL);
    float mean = rs[0] * inv;
    float var  = rq[0] * inv - mean * mean;
    float sc = gamma[l] * rsqrtf(var + 1e-5f);
    params[2*l] = sc;
    params[2*l+1] = beta[l] - mean * sc;
  }
}

// ---------------- resize weight tables ----------------
__global__ void tables_k(int* taj, float* taw, int* tbj, float* tbw, int* tcj, float* tcw) {
  int i = threadIdx.x;
  if (i < 128) {
    // A: 512 -> 128 downsample, antialias kernel_scale = 4, 16 taps
    float sf = 4.f * i + 1.5f;
    int j0 = 4 * i - 6;
    taj[i] = j0;
    float w[16], sum = 0.f;
    for (int t = 0; t < 16; ++t) {
      int j = j0 + t; float ww = 0.f;
      if (j >= 0 && j < 512) ww = keys_cubic(fabsf(sf - (float)j) * 0.25f);
      w[t] = ww; sum += ww;
    }
    for (int t = 0; t < 16; ++t) taw[i*16 + t] = w[t] / sum;
    // B: 64 -> 128 upsample, 4 taps
    float sb = 0.5f * i - 0.25f;
    int jb = (int)floorf(sb) - 1;
    tbj[i] = jb;
    float wb[4], sumb = 0.f;
    for (int t = 0; t < 4; ++t) {
      int j = jb + t; float ww = 0.f;
      if (j >= 0 && j < 64) ww = keys_cubic(fabsf(sb - (float)j));
      wb[t] = ww; sumb += ww;
    }
    for (int t = 0; t < 4; ++t) tbw[i*4 + t] = wb[t] / sumb;
  }
  if (i < 512) {
    // C: 128 -> 512 upsample, 4 taps
    float sc = 0.25f * i - 0.375f;
    int jc = (int)floorf(sc) - 1;
    tcj[i] = jc;
    float wc[4], sumc = 0.f;
    for (int t = 0; t < 4; ++t) {
      int j = jc + t; float ww = 0.f;
      if (j >= 0 && j < 128) ww = keys_cubic(fabsf(sc - (float)j));
      wc[t] = ww; sumc += ww;
    }
    for (int t = 0; t < 4; ++t) tcw[i*4 + t] = wc[t] / sumc;
  }
}

// ---------------- downsample rows: (bl) 512x512 -> 128x512 ----------------
__global__ void down_rows_k(const float* __restrict__ heat, const float* __restrict__ params,
                            const int* __restrict__ taj, const float* __restrict__ taw,
                            float* __restrict__ tmpA) {
  int bl = blockIdx.x >> 7;
  int i  = blockIdx.x & 127;
  int l = bl % L_;
  float sc = params[2*l], sh = params[2*l+1];
  int j0 = taj[i];
  const float* base = heat + (size_t)bl * (HM_*HM_);
  float* out = tmpA + ((size_t)bl * 128 + i) * HM_;
  float w[16];
  #pragma unroll
  for (int t = 0; t < 16; ++t) w[t] = taw[i*16 + t];
  for (int c = threadIdx.x; c < HM_; c += 256) {
    float acc = 0.f;
    #pragma unroll
    for (int t = 0; t < 16; ++t) {
      int j = min(511, max(0, j0 + t));
      acc = fmaf(w[t], fmaf(base[(size_t)j*HM_ + c], sc, sh), acc);
    }
    out[c] = acc;
  }
}

// ---------------- downsample cols: 128x512 -> 128x128 ----------------
__global__ void down_cols_k(const float* __restrict__ tmpA, const int* __restrict__ taj,
                            const float* __restrict__ taw, float* __restrict__ hmrs) {
  __shared__ float row[HM_];
  int bl = blockIdx.x >> 7, i = blockIdx.x & 127;
  const float* src = tmpA + ((size_t)bl * 128 + i) * HM_;
  for (int c = threadIdx.x; c < HM_; c += 128) row[c] = src[c];
  __syncthreads();
  int ic = threadIdx.x;
  int j0 = taj[ic];
  float acc = 0.f;
  #pragma unroll
  for (int t = 0; t < 16; ++t) {
    int j = min(511, max(0, j0 + t));
    acc = fmaf(taw[ic*16 + t], row[j], acc);
  }
  hmrs[((size_t)bl * 128 + i) * 128 + ic] = acc;
}

// ---------------- prior: cond 64x64 -> softplus_b(upsample 128x128) ----------------
__global__ void prior_k(const float* __restrict__ cond, const int* __restrict__ tbj,
                        const float* __restrict__ tbw, float* __restrict__ prior) {
  __shared__ float c64[HC_*HC_];
  int lk = blockIdx.x;
  const float* src = cond + (size_t)lk * HC_*HC_;
  for (int i = threadIdx.x; i < HC_*HC_; i += 256) c64[i] = src[i];
  __syncthreads();
  for (int idx = threadIdx.x; idx < HS_*HS_; idx += 256) {
    int iy = idx >> 7, ix = idx & 127;
    int jy0 = tbj[iy], jx0 = tbj[ix];
    float acc = 0.f;
    #pragma unroll
    for (int ty = 0; ty < 4; ++ty) {
      int jy = min(63, max(0, jy0 + ty));
      float wy = tbw[iy*4 + ty];
      float r = 0.f;
      #pragma unroll
      for (int tx = 0; tx < 4; ++tx) {
        int jx = min(63, max(0, jx0 + tx));
        r = fmaf(tbw[ix*4 + tx], c64[jy*64 + jx], r);
      }
      acc = fmaf(wy, r, acc);
    }
    prior[(size_t)lk * 16384 + idx] = softplus_b(acc);
  }
}

// ---------------- fused direct conv + log + k-sum (atomic) ----------------
// out[y][x] = sum_{s,t} prior[s][t] * like[y+64-s][x+64-t]
__global__ __launch_bounds__(512, 2) void conv_fused_k(
    const float* __restrict__ hmrs, const float* __restrict__ prior,
    const float* __restrict__ bias, const int* __restrict__ vidx,
    float* __restrict__ e128) {
  extern __shared__ float lds[];
  float* P  = lds;               // [128][128]
  float* Lk = lds + 128*128;     // [128][CONV_S], data at col offset +16, zero pads
  int blk = blockIdx.x;
  int b  = blk / (L_*K_);
  int lk = blk % (L_*K_);
  int vl = vidx[lk];
  const float* likes = hmrs + ((size_t)(b*L_ + vl)) * 16384;
  const float* pri   = prior + (size_t)lk * 16384;
  int tid = threadIdx.x;
  for (int i = tid; i < 128*CONV_S; i += 512) Lk[i] = 0.f;
  __syncthreads();
  for (int i = tid; i < 16384; i += 512) {
    P[i] = pri[i];
    int r = i >> 7, c = i & 127;
    Lk[r*CONV_S + 16 + c] = softplus_b(likes[i]);
  }
  __syncthreads();

  int tx = tid & 7, yg = tid >> 3;
  int x0 = tx << 4, y0 = yg << 1;
  float a0[16], a1[16];
  #pragma unroll
  for (int q = 0; q < 16; ++q) { a0[q] = 0.f; a1[q] = 0.f; }

  int sLo = max(0, y0 - 63), sHi = min(127, y0 + 65);
  int tA = (max(0, x0 - 63)) & ~15;
  int tZ = min(127, x0 + 79);

  for (int s = sLo; s <= sHi; ++s) {
    int r0 = y0 + 64 - s;
    const float* Prow = P + (s << 7);
    bool v0 = (unsigned)r0 < 128u;
    bool v1 = (unsigned)(r0 + 1) < 128u;
    const float* L0 = Lk + r0 * CONV_S;
    for (int t0 = tA; t0 <= tZ; t0 += 16) {
      int Bq = x0 + 64 - t0;   // aligned to 16, in [0,128]
      float pr[16];
      #pragma unroll
      for (int q = 0; q < 4; ++q) {
        float4 v = *(const float4*)(Prow + t0 + 4*q);
        pr[4*q] = v.x; pr[4*q+1] = v.y; pr[4*q+2] = v.z; pr[4*q+3] = v.w;
      }
      if (v0) {
        float w[32];
        #pragma unroll
        for (int q = 0; q < 8; ++q) {
          float4 v = *(const float4*)(L0 + Bq + 4*q);
          w[4*q] = v.x; w[4*q+1] = v.y; w[4*q+2] = v.z; w[4*q+3] = v.w;
        }
        #pragma unroll
        for (int dt = 0; dt < 16; ++dt) {
          float p = pr[dt];
          #pragma unroll
          for (int dx = 0; dx < 16; ++dx)
            a0[dx] = fmaf(p, w[16 + dx - dt], a0[dx]);
        }
      }
      if (v1) {
        float w[32];
        #pragma unroll
        for (int q = 0; q < 8; ++q) {
          float4 v = *(const float4*)(L0 + CONV_S + Bq + 4*q);
          w[4*q] = v.x; w[4*q+1] = v.y; w[4*q+2] = v.z; w[4*q+3] = v.w;
        }
        #pragma unroll
        for (int dt = 0; dt < 16; ++dt) {
          float p = pr[dt];
          #pragma unroll
          for (int dx = 0; dx < 16; ++dx)
            a1[dx] = fmaf(p, w[16 + dx - dt], a1[dx]);
        }
      }
    }
  }

  int l = lk >> 3;
  const float* bs = bias + (size_t)lk * 16384;
  float* e = e128 + ((size_t)(b*L_ + l)) * 16384;
  #pragma unroll
  for (int dx = 0; dx < 16; ++dx) {
    int x = x0 + dx;
    float v1_ = a0[dx] + softplus_b(bs[y0*128 + x]) + 1e-6f;
    atomicAdd(&e[y0*128 + x], logf(v1_));
    float v2_ = a1[dx] + softplus_b(bs[(y0+1)*128 + x]) + 1e-6f;
    atomicAdd(&e[(y0+1)*128 + x], logf(v2_));
  }
}

// ---------------- final: upsample energy + loghm, softmax, expectations ----------------
__global__ __launch_bounds__(1024) void final_k(
    const float* __restrict__ heat, const float* __restrict__ params,
    const float* __restrict__ e128, const int* __restrict__ tcj, const float* __restrict__ tcw,
    float* __restrict__ out) {
  __shared__ float red[1024];
  int bl = blockIdx.x;
  int l = bl % L_;
  float sc = params[2*l], sh = params[2*l+1];
  const float* hp = heat + (size_t)bl * (HM_*HM_);
  const float* E  = e128 + (size_t)bl * 16384;
  int tid = threadIdx.x;
  int x = tid & 511;
  int yst = tid >> 9;   // 0 or 1
  int jx0 = tcj[x];
  float wx[4]; int jxc[4];
  #pragma unroll
  for (int t = 0; t < 4; ++t) { wx[t] = tcw[x*4 + t]; jxc[t] = min(127, max(0, jx0 + t)); }

  // pass 1: max
  float mx = -1e30f;
  for (int y = yst; y < HM_; y += 2) {
    int jy0 = tcj[y];
    float acc = 0.f;
    #pragma unroll
    for (int ty = 0; ty < 4; ++ty) {
      int jy = min(127, max(0, jy0 + ty));
      const float* Er = E + jy*128;
      float r = wx[0]*Er[jxc[0]] + wx[1]*Er[jxc[1]] + wx[2]*Er[jxc[2]] + wx[3]*Er[jxc[3]];
      acc = fmaf(tcw[y*4 + ty], r, acc);
    }
    float hm = fmaf(hp[(size_t)y*HM_ + x], sc, sh);
    float e = acc + logf(softplus_b(hm) + 1e-6f);
    mx = fmaxf(mx, e);
  }
  red[tid] = mx; __syncthreads();
  for (int o = 512; o > 0; o >>= 1) {
    if (tid < o) red[tid] = fmaxf(red[tid], red[tid + o]);
    __syncthreads();
  }
  float M = red[0]; __syncthreads();

  // pass 2: sums
  float S = 0.f, Sy = 0.f, Sx = 0.f;
  for (int y = yst; y < HM_; y += 2) {
    int jy0 = tcj[y];
    float acc = 0.f;
    #pragma unroll
    for (int ty = 0; ty < 4; ++ty) {
      int jy = min(127, max(0, jy0 + ty));
      const float* Er = E + jy*128;
      float r = wx[0]*Er[jxc[0]] + wx[1]*Er[jxc[1]] + wx[2]*Er[jxc[2]] + wx[3]*Er[jxc[3]];
      acc = fmaf(tcw[y*4 + ty], r, acc);
    }
    float hm = fmaf(hp[(size_t)y*HM_ + x], sc, sh);
    float e = acc + logf(softplus_b(hm) + 1e-6f);
    float w = expf(e - M);
    S += w; Sy += w * (float)y; Sx += w * (float)x;
  }
  red[tid] = S; __syncthreads();
  for (int o = 512; o > 0; o >>= 1) { if (tid < o) red[tid] += red[tid + o]; __syncthreads(); }
  S = red[0]; __syncthreads();
  red[tid] = Sy; __syncthreads();
  for (int o = 512; o > 0; o >>= 1) { if (tid < o) red[tid] += red[tid + o]; __syncthreads(); }
  Sy = red[0]; __syncthreads();
  red[tid] = Sx; __syncthreads();
  for (int o = 512; o > 0; o >>= 1) { if (tid < o) red[tid] += red[tid + o]; __syncthreads(); }
  Sx = red[0];
  if (tid == 0) {
    out[bl*3 + 0] = 1.f;
    out[bl*3 + 1] = Sy / S;   // ex: weights arange[:,None] = row index
    out[bl*3 + 2] = Sx / S;   // ey: col index
  }
}

extern "C" void kernel_launch(void* const* d_in, const int* in_sizes, int n_in,
                              void* d_out, int out_size, void* d_ws, size_t ws_size,
                              hipStream_t stream) {
  const float* heat  = (const float*)d_in[0];
  const float* cond  = (const float*)d_in[1];
  const float* bias  = (const float*)d_in[2];
  const float* gamma = (const float*)d_in[3];
  const float* beta  = (const float*)d_in[4];
  const int*   vidx  = (const int*)d_in[5];
  float* out = (float*)d_out;
  char* ws = (char*)d_ws;

  float* params = (float*)(ws + OFF_PARAMS);
  int*   taj = (int*)(ws + OFF_TAJ);   float* taw = (float*)(ws + OFF_TAW);
  int*   tbj = (int*)(ws + OFF_TBJ);   float* tbw = (float*)(ws + OFF_TBW);
  int*   tcj = (int*)(ws + OFF_TCJ);   float* tcw = (float*)(ws + OFF_TCW);
  float* tmpA  = (float*)(ws + OFF_TMPA);
  float* hmrs  = (float*)(ws + OFF_HMRS);
  float* prior = (float*)(ws + OFF_PRIOR);
  float* e128  = (float*)(ws + OFF_E128);

  const int convLds = (128*128 + 128*CONV_S) * 4;  // 149504 B
  hipFuncSetAttribute((const void*)conv_fused_k,
                      hipFuncAttributeMaxDynamicSharedMemorySize, convLds);

  hipMemsetAsync(e128, 0, (size_t)74*16384*4, stream);

  bn_stats_k<<<L_, 256, 0, stream>>>(heat, gamma, beta, params);
  tables_k<<<1, 512, 0, stream>>>(taj, taw, tbj, tbw, tcj, tcw);
  down_rows_k<<<74*128, 256, 0, stream>>>(heat, params, taj, taw, tmpA);
  down_cols_k<<<74*128, 128, 0, stream>>>(tmpA, taj, taw, hmrs);
  prior_k<<<L_*K_, 256, 0, stream>>>(cond, tbj, tbw, prior);
  conv_fused_k<<<2*L_*K_, 512, convLds, stream>>>(hmrs, prior, bias, vidx, e128);
  final_k<<<74, 1024, 0, stream>>>(heat, params, e128, tcj, tcw, out);
}

// Round 2
// 958.378 us; speedup vs baseline: 7.9785x; 7.9785x over previous
//
#include <hip/hip_runtime.h>
#include <hip/hip_bf16.h>
#include <math.h>

#define L_ 37
#define K_ 8
#define HM_ 512
#define HS_ 128
#define HC_ 64

using bf16x8 = __attribute__((ext_vector_type(8))) short;
using f32x4  = __attribute__((ext_vector_type(4))) float;

// ---- conv LDS geometry ----
#define LF_FRONT 64
#define LF_STRIDE 192
#define LF_SIZE (LF_FRONT + 128 * LF_STRIDE)   // 24640 floats
#define PB_BYTE (LF_SIZE * 4)                  // 98560 (16B aligned)
#define CONV_LDS (PB_BYTE + 160 * 256)         // 139520 bytes

// ---- ws layout (bytes) ----
static constexpr size_t OFF_SUMS   = 0;                                    // 74 f
static constexpr size_t OFF_PARAMS = 512;                                  // 74 f
static constexpr size_t OFF_TAJ    = 1024;                                 // 128 i
static constexpr size_t OFF_TAW    = 1536;                                 // 2048 f
static constexpr size_t OFF_TBJ    = 9728;                                 // 128 i
static constexpr size_t OFF_TBW    = 10240;                                // 512 f
static constexpr size_t OFF_TCJ    = 12288;                                // 512 i
static constexpr size_t OFF_TCW    = 14336;                                // 2048 f
static constexpr size_t OFF_PART   = 22528;                                // 592*4 f
static constexpr size_t OFF_TMPA   = 32768;                                // 74*128*512 f
static constexpr size_t OFF_HMRS   = OFF_TMPA + (size_t)74*128*512*4;      // 74*16384 f
static constexpr size_t OFF_PIMG   = OFF_HMRS + (size_t)74*16384*4;        // 296*16384 u16
static constexpr size_t OFF_EALL   = OFF_PIMG + (size_t)296*16384*2;       // 592*16384 f
static constexpr size_t OFF_E128   = OFF_EALL + (size_t)592*16384*4;       // 74*16384 f

__device__ __forceinline__ float keys_cubic(float x) {
  float out = ((1.5f * x - 2.5f) * x) * x + 1.f;
  if (x >= 1.f) out = ((-0.5f * x + 2.5f) * x - 4.f) * x + 2.f;
  if (x >= 2.f) out = 0.f;
  return out;
}
__device__ __forceinline__ float sp(float x) {
  float z = 5.f * x;
  return (fmaxf(z, 0.f) + log1pf(expf(-fabsf(z)))) * 0.2f;
}
__device__ __forceinline__ short f2bf(float f) {
  return (short)__builtin_bit_cast(unsigned short, __float2bfloat16(f));
}

// ---------------- BN partial sums ----------------
__global__ void bn_partial_k(const float* __restrict__ heat, float* __restrict__ sums) {
  int l = blockIdx.x >> 4, seg = blockIdx.x & 15;
  int tid = threadIdx.x;
  float s = 0.f, q = 0.f;
  for (int i = tid; i < 8192; i += 256) {
    int f4 = seg * 8192 + i;
    int b = f4 >> 16, rem = f4 & 65535;
    float4 v = ((const float4*)heat)[(size_t)(b * L_ + l) * 65536 + rem];
    s += v.x + v.y + v.z + v.w;
    q += v.x*v.x + v.y*v.y + v.z*v.z + v.w*v.w;
  }
  __shared__ float rs[256], rq[256];
  rs[tid] = s; rq[tid] = q; __syncthreads();
  for (int o = 128; o > 0; o >>= 1) {
    if (tid < o) { rs[tid] += rs[tid + o]; rq[tid] += rq[tid + o]; }
    __syncthreads();
  }
  if (tid == 0) { atomicAdd(&sums[2*l], rs[0]); atomicAdd(&sums[2*l+1], rq[0]); }
}

// ---------------- tables + BN params ----------------
__global__ void tables_k(int* taj, float* taw, int* tbj, float* tbw, int* tcj, float* tcw,
                         const float* __restrict__ sums, const float* __restrict__ gamma,
                         const float* __restrict__ beta, float* __restrict__ params) {
  int i = threadIdx.x;
  if (i < 128) {
    float sf = 4.f * i + 1.5f;
    int j0 = 4 * i - 6;
    taj[i] = j0;
    float w[16], sum = 0.f;
    for (int t = 0; t < 16; ++t) {
      int j = j0 + t; float ww = 0.f;
      if (j >= 0 && j < 512) ww = keys_cubic(fabsf(sf - (float)j) * 0.25f);
      w[t] = ww; sum += ww;
    }
    for (int t = 0; t < 16; ++t) taw[i*16 + t] = w[t] / sum;
    float sb = 0.5f * i - 0.25f;
    int jb = (int)floorf(sb) - 1;
    tbj[i] = jb;
    float wb[4], sumb = 0.f;
    for (int t = 0; t < 4; ++t) {
      int j = jb + t; float ww = 0.f;
      if (j >= 0 && j < 64) ww = keys_cubic(fabsf(sb - (float)j));
      wb[t] = ww; sumb += ww;
    }
    for (int t = 0; t < 4; ++t) tbw[i*4 + t] = wb[t] / sumb;
  }
  if (i < 512) {
    float sc = 0.25f * i - 0.375f;
    int jc = (int)floorf(sc) - 1;
    tcj[i] = jc;
    float wc[4], sumc = 0.f;
    for (int t = 0; t < 4; ++t) {
      int j = jc + t; float ww = 0.f;
      if (j >= 0 && j < 128) ww = keys_cubic(fabsf(sc - (float)j));
      wc[t] = ww; sumc += ww;
    }
    for (int t = 0; t < 4; ++t) tcw[i*4 + t] = wc[t] / sumc;
  }
  if (i < L_) {
    float inv = 1.f / (2.f * HM_ * HM_);
    float mean = sums[2*i] * inv;
    float var  = sums[2*i+1] * inv - mean * mean;
    float sc = gamma[i] * rsqrtf(var + 1e-5f);
    params[2*i] = sc;
    params[2*i+1] = beta[i] - mean * sc;
  }
}

// ---------------- downsample rows: 512x512 -> 128x512 ----------------
__global__ void down_rows_k(const float* __restrict__ heat, const float* __restrict__ params,
                            const int* __restrict__ taj, const float* __restrict__ taw,
                            float* __restrict__ tmpA) {
  int bl = blockIdx.x >> 7;
  int i  = blockIdx.x & 127;
  int l = bl % L_;
  float sc = params[2*l], sh = params[2*l+1];
  int j0 = taj[i];
  const float* base = heat + (size_t)bl * (HM_*HM_);
  float* out = tmpA + ((size_t)bl * 128 + i) * HM_;
  float w[16];
  #pragma unroll
  for (int t = 0; t < 16; ++t) w[t] = taw[i*16 + t];
  for (int c = threadIdx.x; c < HM_; c += 256) {
    float acc = 0.f;
    #pragma unroll
    for (int t = 0; t < 16; ++t) {
      int j = min(511, max(0, j0 + t));
      acc = fmaf(w[t], fmaf(base[(size_t)j*HM_ + c], sc, sh), acc);
    }
    out[c] = acc;
  }
}

// ---------------- downsample cols: 128x512 -> 128x128 ----------------
__global__ void down_cols_k(const float* __restrict__ tmpA, const int* __restrict__ taj,
                            const float* __restrict__ taw, float* __restrict__ hmrs) {
  __shared__ float row[HM_];
  int bl = blockIdx.x >> 7, i = blockIdx.x & 127;
  const float* src = tmpA + ((size_t)bl * 128 + i) * HM_;
  for (int c = threadIdx.x; c < HM_; c += 128) row[c] = src[c];
  __syncthreads();
  int ic = threadIdx.x;
  int j0 = taj[ic];
  float acc = 0.f;
  #pragma unroll
  for (int t = 0; t < 16; ++t) {
    int j = min(511, max(0, j0 + t));
    acc = fmaf(taw[ic*16 + t], row[j], acc);
  }
  hmrs[((size_t)bl * 128 + i) * 128 + ic] = acc;
}

// ---------------- prior: sp(upsample(cond)) -> reversed + swizzled bf16 image ----------------
// image row s (128 u16): chunk cc holds logical Prev chunk (cc ^ (s&7)); Prev[s][jj] = P[s][127-jj]
__global__ void prior_rev_k(const float* __restrict__ cond, const int* __restrict__ tbj,
                            const float* __restrict__ tbw, unsigned short* __restrict__ pimg) {
  __shared__ float c64[HC_*HC_];
  int lk = blockIdx.x;
  const float* src = cond + (size_t)lk * HC_*HC_;
  for (int i = threadIdx.x; i < HC_*HC_; i += 256) c64[i] = src[i];
  __syncthreads();
  // 2048 chunk tasks: s = t>>4, jblk = t&15 covers j = jblk*8 .. +7
  for (int t = threadIdx.x; t < 2048; t += 256) {
    int s = t >> 4, jblk = t & 15;
    int jy0 = tbj[s];
    float wy[4]; int jys[4];
    #pragma unroll
    for (int q = 0; q < 4; ++q) { wy[q] = tbw[s*4+q]; jys[q] = min(63, max(0, jy0 + q)); }
    unsigned short pk[8];
    #pragma unroll
    for (int ii = 0; ii < 8; ++ii) {
      int j = jblk * 8 + ii;
      int jx0 = tbj[j];
      float acc = 0.f;
      #pragma unroll
      for (int q = 0; q < 4; ++q) {
        int jy = jys[q];
        float r = 0.f;
        #pragma unroll
        for (int tx = 0; tx < 4; ++tx) {
          int jx = min(63, max(0, jx0 + tx));
          r = fmaf(tbw[j*4 + tx], c64[jy*64 + jx], r);
        }
        acc = fmaf(wy[q], r, acc);
      }
      pk[7 - ii] = (unsigned short)f2bf(sp(acc));   // jj = 127-j -> pos 7-ii in chunk 15-jblk
    }
    int cc = (15 - jblk) ^ (s & 7);
    unsigned short* dst = pimg + (size_t)lk * 16384 + s * 128 + cc * 8;
    *(ushort4*)(dst)     = make_ushort4(pk[0], pk[1], pk[2], pk[3]);
    *(ushort4*)(dst + 4) = make_ushort4(pk[4], pk[5], pk[6], pk[7]);
  }
}

// ---------------- conv: implicit-Toeplitz bf16 MFMA ----------------
// out[y][x] = sum_u sum_t P[y+64-u][t] * L[u][x+64-t]
// per-u GEMM 16x16x32: t-chunk kc: t = 32*kc + 31 - k
//   A[m][k] = Prev[s][96-32kc+k], s = y0+m+64-u  (Prev = P reversed in t)
//   B[k][n] = L[u][x0+n+33-32kc+k]  (fp32 gather, 8 consecutive)
__global__ __launch_bounds__(512) void conv_mfma_k(
    const float* __restrict__ hmrs, const unsigned short* __restrict__ pimg,
    const float* __restrict__ bias, const int* __restrict__ vidx,
    float* __restrict__ e_all) {
  extern __shared__ char lds[];
  float* Lf = (float*)lds;
  unsigned short* Pb = (unsigned short*)(lds + PB_BYTE);   // 160 rows x 128 (r = s+16)
  int blk = blockIdx.x;
  int b = blk / 296, lk = blk % 296;
  int tid = threadIdx.x;

  // ---- stage: zero Lf pads (front 64 + per-row gap 64) ----
  for (int i = tid; i < 64 + 128*64; i += 512) {
    int a = (i < 64) ? i : (64 + ((i - 64) >> 6) * LF_STRIDE + 128 + ((i - 64) & 63));
    Lf[a] = 0.f;
  }
  // zero Pb pad rows 0..15, 144..159 (as u32)
  {
    unsigned* pz = (unsigned*)Pb;
    for (int i = tid; i < 2048; i += 512) {
      int r = i >> 6, c = i & 63;
      int row = (r < 16) ? r : (r + 128);
      pz[row * 64 + c] = 0u;
    }
  }
  // Lf data = sp(likes)
  int vl = vidx[lk];
  const float4* likes4 = (const float4*)(hmrs + (size_t)(b * L_ + vl) * 16384);
  for (int i = tid; i < 4096; i += 512) {
    float4 v = likes4[i];
    int u = i >> 5, c = (i & 31) << 2;
    float4 o;
    o.x = sp(v.x); o.y = sp(v.y); o.z = sp(v.z); o.w = sp(v.w);
    *(float4*)(Lf + LF_FRONT + u * LF_STRIDE + c) = o;
  }
  // Pb data rows 16..143 = linear copy of pre-swizzled image
  {
    const float4* src = (const float4*)(pimg + (size_t)lk * 16384);
    float4* dst = (float4*)(Pb + 16 * 128);
    for (int i = tid; i < 2048; i += 512) dst[i] = src[i];
  }
  __syncthreads();

  int wid = tid >> 6, lane = tid & 63;
  int wm = wid >> 2, wn = wid & 3;
  int l15 = lane & 15, kg = lane >> 4;
  int xb = wn * 32;
  int lane_b = LF_FRONT + 33 + l15 + 8 * kg;

  f32x4 acc[4][2];
  #pragma unroll
  for (int mt = 0; mt < 4; ++mt)
    #pragma unroll
    for (int nt = 0; nt < 2; ++nt)
      #pragma unroll
      for (int j = 0; j < 4; ++j) acc[mt][nt][j] = 0.f;

  int u_lo = max(0, 64 * wm - 63);
  for (int u = u_lo; u <= 127; ++u) {
    int ubase = u * LF_STRIDE;
    #pragma unroll
    for (int kc = 0; kc < 4; ++kc) {
      bf16x8 Bf[2];
      #pragma unroll
      for (int nt = 0; nt < 2; ++nt) {
        int idx = ubase + lane_b + xb + nt * 16 - 32 * kc;
        float v0 = Lf[idx+0], v1 = Lf[idx+1], v2 = Lf[idx+2], v3 = Lf[idx+3];
        float v4 = Lf[idx+4], v5 = Lf[idx+5], v6 = Lf[idx+6], v7 = Lf[idx+7];
        bf16x8 t;
        t[0]=f2bf(v0); t[1]=f2bf(v1); t[2]=f2bf(v2); t[3]=f2bf(v3);
        t[4]=f2bf(v4); t[5]=f2bf(v5); t[6]=f2bf(v6); t[7]=f2bf(v7);
        Bf[nt] = t;
      }
      int cA = 12 - 4 * kc + kg;
      #pragma unroll
      for (int mt = 0; mt < 4; ++mt) {
        int y0 = 64 * wm + 16 * mt;
        if (u < y0 - 63 || u > y0 + 79) continue;
        int r = y0 + l15 + 80 - u;                  // = s + 16, in [1,158]
        bf16x8 Af = *(const bf16x8*)(lds + PB_BYTE + r * 256 + ((cA ^ (r & 7)) << 4));
        acc[mt][0] = __builtin_amdgcn_mfma_f32_16x16x32_bf16(Af, Bf[0], acc[mt][0], 0, 0, 0);
        acc[mt][1] = __builtin_amdgcn_mfma_f32_16x16x32_bf16(Af, Bf[1], acc[mt][1], 0, 0, 0);
      }
    }
  }

  // ---- epilogue: log(conv + sp(bias) + delta) -> e_all slice ----
  const float* bs = bias + (size_t)lk * 16384;
  float* eo = e_all + (size_t)(b * 296 + lk) * 16384;
  int row0 = kg * 4;
  #pragma unroll
  for (int mt = 0; mt < 4; ++mt) {
    #pragma unroll
    for (int nt = 0; nt < 2; ++nt) {
      int x = xb + nt * 16 + l15;
      int yb = 64 * wm + 16 * mt + row0;
      #pragma unroll
      for (int rr = 0; rr < 4; ++rr) {
        int y = yb + rr;
        float v = acc[mt][nt][rr] + sp(bs[y * 128 + x]) + 1e-6f;
        eo[y * 128 + x] = logf(v);
      }
    }
  }
}

// ---------------- sum energies over k ----------------
__global__ void esum_k(const float* __restrict__ e_all, float* __restrict__ e128) {
  int bl = blockIdx.x; int tid = threadIdx.x;
  const float4* src = (const float4*)(e_all + (size_t)bl * 8 * 16384);
  float4* dst = (float4*)(e128 + (size_t)bl * 16384);
  for (int i = tid; i < 4096; i += 256) {
    float4 a = src[i];
    #pragma unroll
    for (int k = 1; k < 8; ++k) {
      float4 v = src[k * 4096 + i];
      a.x += v.x; a.y += v.y; a.z += v.z; a.w += v.w;
    }
    dst[i] = a;
  }
}

// ---------------- final: online softmax partials over 64-row segments ----------------
__global__ __launch_bounds__(256) void final_partial_k(
    const float* __restrict__ heat, const float* __restrict__ params,
    const float* __restrict__ e128, const int* __restrict__ tcj, const float* __restrict__ tcw,
    float* __restrict__ partials) {
  __shared__ float Elds[20 * 128];
  __shared__ float rm[256], rS[256], ry[256], rx[256];
  int blk = blockIdx.x;
  int bl = blk >> 3, seg = blk & 7;
  int l = bl % L_;
  int tid = threadIdx.x;
  float sc = params[2*l], sh = params[2*l+1];
  int y_lo = seg * 64;
  int r_lo = max(0, tcj[y_lo]);
  int r_hi = min(127, tcj[y_lo + 63] + 3);
  int nrows = r_hi - r_lo + 1;
  const float* E = e128 + (size_t)bl * 16384;
  for (int i = tid; i < nrows * 128; i += 256) Elds[i] = E[r_lo * 128 + i];
  __syncthreads();

  float wx[2][4]; int jx[2][4];
  #pragma unroll
  for (int xi = 0; xi < 2; ++xi) {
    int x = tid + xi * 256;
    int j0 = tcj[x];
    #pragma unroll
    for (int t = 0; t < 4; ++t) { wx[xi][t] = tcw[x*4 + t]; jx[xi][t] = min(127, max(0, j0 + t)); }
  }

  float m = -1e30f, S = 0.f, Sy = 0.f, Sx = 0.f;
  for (int y = y_lo; y < y_lo + 64; ++y) {
    int jy0 = tcj[y];
    float wy[4]; int jyr[4];
    #pragma unroll
    for (int t = 0; t < 4; ++t) { wy[t] = tcw[y*4 + t]; jyr[t] = min(127, max(0, jy0 + t)) - r_lo; }
    #pragma unroll
    for (int xi = 0; xi < 2; ++xi) {
      int x = tid + xi * 256;
      float a = 0.f;
      #pragma unroll
      for (int t = 0; t < 4; ++t) {
        const float* Er = Elds + jyr[t] * 128;
        float rrow = wx[xi][0]*Er[jx[xi][0]] + wx[xi][1]*Er[jx[xi][1]]
                   + wx[xi][2]*Er[jx[xi][2]] + wx[xi][3]*Er[jx[xi][3]];
        a = fmaf(wy[t], rrow, a);
      }
      float hm = fmaf(heat[(size_t)bl * 262144 + y * 512 + x], sc, sh);
      float e = a + logf(sp(hm) + 1e-6f);
      if (e > m) {
        float f = expf(m - e);
        S *= f; Sy *= f; Sx *= f; m = e;
      }
      float w = expf(e - m);
      S += w; Sy = fmaf(w, (float)y, Sy); Sx = fmaf(w, (float)x, Sx);
    }
  }
  rm[tid] = m; rS[tid] = S; ry[tid] = Sy; rx[tid] = Sx; __syncthreads();
  for (int o = 128; o > 0; o >>= 1) {
    if (tid < o) {
      float ma = rm[tid], mb = rm[tid + o];
      float M = fmaxf(ma, mb);
      float fa = expf(ma - M), fb = expf(mb - M);
      rS[tid] = rS[tid]*fa + rS[tid+o]*fb;
      ry[tid] = ry[tid]*fa + ry[tid+o]*fb;
      rx[tid] = rx[tid]*fa + rx[tid+o]*fb;
      rm[tid] = M;
    }
    __syncthreads();
  }
  if (tid == 0) {
    float* p = partials + (size_t)blk * 4;
    p[0] = rm[0]; p[1] = rS[0]; p[2] = ry[0]; p[3] = rx[0];
  }
}

__global__ void final_combine_k(const float* __restrict__ partials, float* __restrict__ out) {
  int bl = blockIdx.x;
  if (threadIdx.x != 0) return;
  float M = -1e30f, S = 0.f, Sy = 0.f, Sx = 0.f;
  for (int i = 0; i < 8; ++i) {
    const float* p = partials + (size_t)(bl * 8 + i) * 4;
    float m2 = p[0], s2 = p[1], sy2 = p[2], sx2 = p[3];
    float Mn = fmaxf(M, m2);
    float fa = expf(M - Mn), fb = expf(m2 - Mn);
    S = S*fa + s2*fb; Sy = Sy*fa + sy2*fb; Sx = Sx*fa + sx2*fb; M = Mn;
  }
  out[bl*3 + 0] = 1.f;
  out[bl*3 + 1] = Sy / S;
  out[bl*3 + 2] = Sx / S;
}

extern "C" void kernel_launch(void* const* d_in, const int* in_sizes, int n_in,
                              void* d_out, int out_size, void* d_ws, size_t ws_size,
                              hipStream_t stream) {
  const float* heat  = (const float*)d_in[0];
  const float* cond  = (const float*)d_in[1];
  const float* bias  = (const float*)d_in[2];
  const float* gamma = (const float*)d_in[3];
  const float* beta  = (const float*)d_in[4];
  const int*   vidx  = (const int*)d_in[5];
  float* out = (float*)d_out;
  char* ws = (char*)d_ws;

  float* sums   = (float*)(ws + OFF_SUMS);
  float* params = (float*)(ws + OFF_PARAMS);
  int*   taj = (int*)(ws + OFF_TAJ);   float* taw = (float*)(ws + OFF_TAW);
  int*   tbj = (int*)(ws + OFF_TBJ);   float* tbw = (float*)(ws + OFF_TBW);
  int*   tcj = (int*)(ws + OFF_TCJ);   float* tcw = (float*)(ws + OFF_TCW);
  float* part  = (float*)(ws + OFF_PART);
  float* tmpA  = (float*)(ws + OFF_TMPA);
  float* hmrs  = (float*)(ws + OFF_HMRS);
  unsigned short* pimg = (unsigned short*)(ws + OFF_PIMG);
  float* e_all = (float*)(ws + OFF_EALL);
  float* e128  = (float*)(ws + OFF_E128);

  hipFuncSetAttribute((const void*)conv_mfma_k,
                      hipFuncAttributeMaxDynamicSharedMemorySize, CONV_LDS);

  hipMemsetAsync(sums, 0, 2 * L_ * sizeof(float), stream);
  bn_partial_k<<<L_ * 16, 256, 0, stream>>>(heat, sums);
  tables_k<<<1, 512, 0, stream>>>(taj, taw, tbj, tbw, tcj, tcw, sums, gamma, beta, params);
  down_rows_k<<<74 * 128, 256, 0, stream>>>(heat, params, taj, taw, tmpA);
  down_cols_k<<<74 * 128, 128, 0, stream>>>(tmpA, taj, taw, hmrs);
  prior_rev_k<<<L_ * K_, 256, 0, stream>>>(cond, tbj, tbw, pimg);
  conv_mfma_k<<<2 * L_ * K_, 512, CONV_LDS, stream>>>(hmrs, pimg, bias, vidx, e_all);
  esum_k<<<74, 256, 0, stream>>>(e_all, e128);
  final_partial_k<<<74 * 8, 256, 0, stream>>>(heat, params, e128, tcj, tcw, part);
  final_combine_k<<<74, 64, 0, stream>>>(part, out);
}

// Round 4
// 656.993 us; speedup vs baseline: 11.6385x; 1.4587x over previous
//
#include <hip/hip_runtime.h>
#include <hip/hip_bf16.h>
#include <math.h>

#define L_ 37
#define K_ 8
#define HM_ 512
#define HS_ 128
#define HC_ 64

using f32x4 = __attribute__((ext_vector_type(4))) float;

// ---- conv LDS geometry (fp8) ----
// L region: front 64 zeros + 128 rows, stride 192 bytes (128 data + 64 zero gap),
// + 16B tail pad for over-read of the dword-aligned 12B window. All offsets bytes.
#define L_REGION 24656                    // 64 + 128*192 + 16, 16B aligned
#define PB_OFF   L_REGION                 // P: 158 rows x 128B (15 pad + 128 data + 15 pad)
#define CONV_LDS (PB_OFF + 158*128)       // 44880 bytes -> 3 blocks/CU

// ---- ws layout (bytes) ----
static constexpr size_t OFF_SUMS   = 0;                                    // 74 f
static constexpr size_t OFF_PARAMS = 512;                                  // 74 f
static constexpr size_t OFF_TAJ    = 1024;                                 // 128 i
static constexpr size_t OFF_TAW    = 1536;                                 // 2048 f
static constexpr size_t OFF_TBJ    = 9728;                                 // 128 i
static constexpr size_t OFF_TBW    = 10240;                                // 512 f
static constexpr size_t OFF_TCJ    = 12288;                                // 512 i
static constexpr size_t OFF_TCW    = 14336;                                // 2048 f
static constexpr size_t OFF_PART   = 22528;                                // 592*4 f
static constexpr size_t OFF_TMPA   = 32768;                                // 74*128*512 f
static constexpr size_t OFF_HMRS   = OFF_TMPA + (size_t)74*128*512*4;      // 74*16384 f
static constexpr size_t OFF_PIMG   = OFF_HMRS + (size_t)74*16384*4;        // 296*16384 u8
static constexpr size_t OFF_EALL   = OFF_PIMG + (size_t)296*16384;         // 592*16384 f
static constexpr size_t OFF_E128   = OFF_EALL + (size_t)592*16384*4;       // 74*16384 f

__device__ __forceinline__ float keys_cubic(float x) {
  float out = ((1.5f * x - 2.5f) * x) * x + 1.f;
  if (x >= 1.f) out = ((-0.5f * x + 2.5f) * x - 4.f) * x + 2.f;
  if (x >= 2.f) out = 0.f;
  return out;
}
__device__ __forceinline__ float sp(float x) {
  float z = 5.f * x;
  return (fmaxf(z, 0.f) + log1pf(expf(-fabsf(z)))) * 0.2f;
}

// ---------------- BN partial sums ----------------
__global__ void bn_partial_k(const float* __restrict__ heat, float* __restrict__ sums) {
  int l = blockIdx.x >> 4, seg = blockIdx.x & 15;
  int tid = threadIdx.x;
  float s = 0.f, q = 0.f;
  for (int i = tid; i < 8192; i += 256) {
    int f4 = seg * 8192 + i;
    int b = f4 >> 16, rem = f4 & 65535;
    float4 v = ((const float4*)heat)[(size_t)(b * L_ + l) * 65536 + rem];
    s += v.x + v.y + v.z + v.w;
    q += v.x*v.x + v.y*v.y + v.z*v.z + v.w*v.w;
  }
  __shared__ float rs[256], rq[256];
  rs[tid] = s; rq[tid] = q; __syncthreads();
  for (int o = 128; o > 0; o >>= 1) {
    if (tid < o) { rs[tid] += rs[tid + o]; rq[tid] += rq[tid + o]; }
    __syncthreads();
  }
  if (tid == 0) { atomicAdd(&sums[2*l], rs[0]); atomicAdd(&sums[2*l+1], rq[0]); }
}

// ---------------- tables + BN params ----------------
__global__ void tables_k(int* taj, float* taw, int* tbj, float* tbw, int* tcj, float* tcw,
                         const float* __restrict__ sums, const float* __restrict__ gamma,
                         const float* __restrict__ beta, float* __restrict__ params) {
  int i = threadIdx.x;
  if (i < 128) {
    float sf = 4.f * i + 1.5f;
    int j0 = 4 * i - 6;
    taj[i] = j0;
    float w[16], sum = 0.f;
    for (int t = 0; t < 16; ++t) {
      int j = j0 + t; float ww = 0.f;
      if (j >= 0 && j < 512) ww = keys_cubic(fabsf(sf - (float)j) * 0.25f);
      w[t] = ww; sum += ww;
    }
    for (int t = 0; t < 16; ++t) taw[i*16 + t] = w[t] / sum;
    float sb = 0.5f * i - 0.25f;
    int jb = (int)floorf(sb) - 1;
    tbj[i] = jb;
    float wb[4], sumb = 0.f;
    for (int t = 0; t < 4; ++t) {
      int j = jb + t; float ww = 0.f;
      if (j >= 0 && j < 64) ww = keys_cubic(fabsf(sb - (float)j));
      wb[t] = ww; sumb += ww;
    }
    for (int t = 0; t < 4; ++t) tbw[i*4 + t] = wb[t] / sumb;
  }
  if (i < 512) {
    float sc = 0.25f * i - 0.375f;
    int jc = (int)floorf(sc) - 1;
    tcj[i] = jc;
    float wc[4], sumc = 0.f;
    for (int t = 0; t < 4; ++t) {
      int j = jc + t; float ww = 0.f;
      if (j >= 0 && j < 128) ww = keys_cubic(fabsf(sc - (float)j));
      wc[t] = ww; sumc += ww;
    }
    for (int t = 0; t < 4; ++t) tcw[i*4 + t] = wc[t] / sumc;
  }
  if (i < L_) {
    float inv = 1.f / (2.f * HM_ * HM_);
    float mean = sums[2*i] * inv;
    float var  = sums[2*i+1] * inv - mean * mean;
    float sc = gamma[i] * rsqrtf(var + 1e-5f);
    params[2*i] = sc;
    params[2*i+1] = beta[i] - mean * sc;
  }
}

// ---------------- downsample rows: 512x512 -> 128x512 ----------------
__global__ void down_rows_k(const float* __restrict__ heat, const float* __restrict__ params,
                            const int* __restrict__ taj, const float* __restrict__ taw,
                            float* __restrict__ tmpA) {
  int bl = blockIdx.x >> 7;
  int i  = blockIdx.x & 127;
  int l = bl % L_;
  float sc = params[2*l], sh = params[2*l+1];
  int j0 = taj[i];
  const float* base = heat + (size_t)bl * (HM_*HM_);
  float* out = tmpA + ((size_t)bl * 128 + i) * HM_;
  float w[16];
  #pragma unroll
  for (int t = 0; t < 16; ++t) w[t] = taw[i*16 + t];
  for (int c = threadIdx.x; c < HM_; c += 256) {
    float acc = 0.f;
    #pragma unroll
    for (int t = 0; t < 16; ++t) {
      int j = min(511, max(0, j0 + t));
      acc = fmaf(w[t], fmaf(base[(size_t)j*HM_ + c], sc, sh), acc);
    }
    out[c] = acc;
  }
}

// ---------------- downsample cols: 128x512 -> 128x128 ----------------
__global__ void down_cols_k(const float* __restrict__ tmpA, const int* __restrict__ taj,
                            const float* __restrict__ taw, float* __restrict__ hmrs) {
  __shared__ float row[HM_];
  int bl = blockIdx.x >> 7, i = blockIdx.x & 127;
  const float* src = tmpA + ((size_t)bl * 128 + i) * HM_;
  for (int c = threadIdx.x; c < HM_; c += 128) row[c] = src[c];
  __syncthreads();
  int ic = threadIdx.x;
  int j0 = taj[ic];
  float acc = 0.f;
  #pragma unroll
  for (int t = 0; t < 16; ++t) {
    int j = min(511, max(0, j0 + t));
    acc = fmaf(taw[ic*16 + t], row[j], acc);
  }
  hmrs[((size_t)bl * 128 + i) * 128 + ic] = acc;
}

// ---------------- prior: sp(upsample(cond)) -> reversed + swizzled fp8 image ----------------
// image row s (128 u8): chunk cc (8B) holds logical Prev chunk (cc ^ (s&7)); Prev[s][jj]=P[s][127-jj]
__global__ void prior_rev_k(const float* __restrict__ cond, const int* __restrict__ tbj,
                            const float* __restrict__ tbw, unsigned char* __restrict__ pimg) {
  __shared__ float c64[HC_*HC_];
  int lk = blockIdx.x;
  const float* src = cond + (size_t)lk * HC_*HC_;
  for (int i = threadIdx.x; i < HC_*HC_; i += 256) c64[i] = src[i];
  __syncthreads();
  for (int t = threadIdx.x; t < 2048; t += 256) {
    int s = t >> 4, jblk = t & 15;
    int jy0 = tbj[s];
    float wy[4]; int jys[4];
    #pragma unroll
    for (int q = 0; q < 4; ++q) { wy[q] = tbw[s*4+q]; jys[q] = min(63, max(0, jy0 + q)); }
    float v[8];
    #pragma unroll
    for (int ii = 0; ii < 8; ++ii) {
      int j = jblk * 8 + ii;
      int jx0 = tbj[j];
      float acc = 0.f;
      #pragma unroll
      for (int q = 0; q < 4; ++q) {
        int jy = jys[q];
        float r = 0.f;
        #pragma unroll
        for (int tx = 0; tx < 4; ++tx) {
          int jx = min(63, max(0, jx0 + tx));
          r = fmaf(tbw[j*4 + tx], c64[jy*64 + jx], r);
        }
        acc = fmaf(wy[q], r, acc);
      }
      v[ii] = sp(acc);
    }
    // byte m of chunk = value for ii = 7-m
    int w0 = 0, w1 = 0;
    w0 = __builtin_amdgcn_cvt_pk_fp8_f32(v[7], v[6], w0, false);
    w0 = __builtin_amdgcn_cvt_pk_fp8_f32(v[5], v[4], w0, true);
    w1 = __builtin_amdgcn_cvt_pk_fp8_f32(v[3], v[2], w1, false);
    w1 = __builtin_amdgcn_cvt_pk_fp8_f32(v[1], v[0], w1, true);
    int cc = (15 - jblk) ^ (s & 7);
    uint2* dst = (uint2*)(pimg + (size_t)lk * 16384 + s * 128 + cc * 8);
    *dst = make_uint2((unsigned)w0, (unsigned)w1);
  }
}

// ---------------- conv: implicit-Toeplitz fp8 MFMA ----------------
// out[y][x] = sum_u sum_t P[y+64-u][t] * L[u][x+64-t]
// k-chunk kc: t = 32*kc + 31 - k, k = 8*kg + j
//   A[m][k] = Prev[s][96-32kc+k], s = y0+m+64-u   (8B aligned read, swizzled)
//   B[k][n] = L[u][x0+n+33-32kc+k]                (byte window, funnel-shift extract)
__global__ __launch_bounds__(512) void conv_mfma_k(
    const float* __restrict__ hmrs, const unsigned char* __restrict__ pimg,
    const float* __restrict__ bias, const int* __restrict__ vidx,
    float* __restrict__ e_all) {
  extern __shared__ char lds[];
  int blk = blockIdx.x;
  int b = blk / 296, lk = blk % 296;
  int tid = threadIdx.x;

  // ---- zero L front(64B)+tail pad(16B)+gaps(128*64B), as dwords ----
  {
    unsigned* lz = (unsigned*)lds;
    for (int i = tid; i < 16 + 4 + 2048; i += 512) {
      int a;
      if (i < 16) a = i;
      else if (i < 20) a = 6160 + (i - 16);           // 24640/4
      else { int g = i - 20; int u = g >> 4, c = g & 15; a = 48*u + 48 + c; }
      lz[a] = 0u;
    }
  }
  // ---- zero P pad rows 0..14 and 143..157 ----
  {
    unsigned* pz = (unsigned*)(lds + PB_OFF);
    for (int i = tid; i < 960; i += 512) {
      int a = (i < 480) ? i : (18304/4 + (i - 480));
      pz[a] = 0u;
    }
  }
  // ---- stage L = fp8(sp(likes)), rows at byte 64+192u ----
  int vl = vidx[lk];
  const float4* likes4 = (const float4*)(hmrs + (size_t)(b * L_ + vl) * 16384);
  for (int i = tid; i < 1024; i += 512) {
    int u = i >> 3, c16 = (i & 7) << 4;
    int base4 = u * 32 + (c16 >> 2);
    unsigned wds[4];
    #pragma unroll
    for (int q = 0; q < 4; ++q) {
      float4 v = likes4[base4 + q];
      int w = 0;
      w = __builtin_amdgcn_cvt_pk_fp8_f32(sp(v.x), sp(v.y), w, false);
      w = __builtin_amdgcn_cvt_pk_fp8_f32(sp(v.z), sp(v.w), w, true);
      wds[q] = (unsigned)w;
    }
    *(uint4*)(lds + 64 + 192*u + c16) = make_uint4(wds[0], wds[1], wds[2], wds[3]);
  }
  // ---- stage P data rows 15..142 = linear copy of pre-swizzled image ----
  {
    const uint4* src = (const uint4*)(pimg + (size_t)lk * 16384);
    uint4* dst = (uint4*)(lds + PB_OFF + 15*128);
    for (int i = tid; i < 1024; i += 512) dst[i] = src[i];
  }
  __syncthreads();

  int wid = tid >> 6, lane = tid & 63;
  int wm = wid >> 2, wn = wid & 3;
  int l15 = lane & 15, kg = lane >> 4;
  int xb = wn * 32;
  int par4 = (1 + l15) & 3;
  int shiftB = par4 << 3;
  int C0 = 1 + l15 + 8*kg + xb - par4;   // byte base bias (kc-max folded into offsets)

  f32x4 acc[4][2];
  #pragma unroll
  for (int mt = 0; mt < 4; ++mt)
    #pragma unroll
    for (int nt = 0; nt < 2; ++nt)
      #pragma unroll
      for (int j = 0; j < 4; ++j) acc[mt][nt][j] = 0.f;

  int u_lo = max(0, 64 * wm - 63);
  for (int u = u_lo; u <= 127; ++u) {
    const unsigned* bp = (const unsigned*)(lds + C0 + 192*u);
    #pragma unroll
    for (int kc = 0; kc < 4; ++kc) {
      if (xb + 95 - 32*kc < 0 || xb + 33 - 32*kc > 127) continue;  // dead window
      long Bf[2];
      #pragma unroll
      for (int nt = 0; nt < 2; ++nt) {
        int q = 24 + 4*nt - 8*kc;
        unsigned d0 = bp[q], d1 = bp[q+1], d2 = bp[q+2];
        unsigned b0 = (unsigned)((((unsigned long long)d1 << 32) | d0) >> shiftB);
        unsigned b1 = (unsigned)((((unsigned long long)d2 << 32) | d1) >> shiftB);
        Bf[nt] = (long)(((unsigned long long)b1 << 32) | b0);
      }
      int cA16 = (12 - 4*kc + kg);
      #pragma unroll
      for (int mt = 0; mt < 4; ++mt) {
        int y0 = 64 * wm + 16 * mt;
        if (u < y0 - 63 || u > y0 + 79) continue;
        int rr = y0 + l15 + 79 - u;                 // 0..157
        int swz = (cA16 ^ ((rr + 1) & 7)) << 3;
        long Af = *(const long*)(lds + PB_OFF + rr * 128 + swz);
        acc[mt][0] = __builtin_amdgcn_mfma_f32_16x16x32_fp8_fp8(Af, Bf[0], acc[mt][0], 0, 0, 0);
        acc[mt][1] = __builtin_amdgcn_mfma_f32_16x16x32_fp8_fp8(Af, Bf[1], acc[mt][1], 0, 0, 0);
      }
    }
  }

  // ---- epilogue: log(conv + sp(bias) + delta) -> e_all slice ----
  const float* bs = bias + (size_t)lk * 16384;
  float* eo = e_all + (size_t)(b * 296 + lk) * 16384;
  int row0 = kg * 4;
  #pragma unroll
  for (int mt = 0; mt < 4; ++mt) {
    #pragma unroll
    for (int nt = 0; nt < 2; ++nt) {
      int x = xb + nt * 16 + l15;
      int yb = 64 * wm + 16 * mt + row0;
      #pragma unroll
      for (int rr = 0; rr < 4; ++rr) {
        int y = yb + rr;
        float v = acc[mt][nt][rr] + sp(bs[y * 128 + x]) + 1e-6f;
        eo[y * 128 + x] = logf(v);
      }
    }
  }
}

// ---------------- sum energies over k ----------------
__global__ void esum_k(const float* __restrict__ e_all, float* __restrict__ e128) {
  int bl = blockIdx.x; int tid = threadIdx.x;
  const float4* src = (const float4*)(e_all + (size_t)bl * 8 * 16384);
  float4* dst = (float4*)(e128 + (size_t)bl * 16384);
  for (int i = tid; i < 4096; i += 256) {
    float4 a = src[i];
    #pragma unroll
    for (int k = 1; k < 8; ++k) {
      float4 v = src[k * 4096 + i];
      a.x += v.x; a.y += v.y; a.z += v.z; a.w += v.w;
    }
    dst[i] = a;
  }
}

// ---------------- final: online softmax partials over 64-row segments ----------------
__global__ __launch_bounds__(256) void final_partial_k(
    const float* __restrict__ heat, const float* __restrict__ params,
    const float* __restrict__ e128, const int* __restrict__ tcj, const float* __restrict__ tcw,
    float* __restrict__ partials) {
  __shared__ float Elds[20 * 128];
  __shared__ float rm[256], rS[256], ry[256], rx[256];
  int blk = blockIdx.x;
  int bl = blk >> 3, seg = blk & 7;
  int l = bl % L_;
  int tid = threadIdx.x;
  float sc = params[2*l], sh = params[2*l+1];
  int y_lo = seg * 64;
  int r_lo = max(0, tcj[y_lo]);
  int r_hi = min(127, tcj[y_lo + 63] + 3);
  int nrows = r_hi - r_lo + 1;
  const float* E = e128 + (size_t)bl * 16384;
  for (int i = tid; i < nrows * 128; i += 256) Elds[i] = E[r_lo * 128 + i];
  __syncthreads();

  float wx[2][4]; int jx[2][4];
  #pragma unroll
  for (int xi = 0; xi < 2; ++xi) {
    int x = tid + xi * 256;
    int j0 = tcj[x];
    #pragma unroll
    for (int t = 0; t < 4; ++t) { wx[xi][t] = tcw[x*4 + t]; jx[xi][t] = min(127, max(0, j0 + t)); }
  }

  float m = -1e30f, S = 0.f, Sy = 0.f, Sx = 0.f;
  for (int y = y_lo; y < y_lo + 64; ++y) {
    int jy0 = tcj[y];
    float wy[4]; int jyr[4];
    #pragma unroll
    for (int t = 0; t < 4; ++t) { wy[t] = tcw[y*4 + t]; jyr[t] = min(127, max(0, jy0 + t)) - r_lo; }
    #pragma unroll
    for (int xi = 0; xi < 2; ++xi) {
      int x = tid + xi * 256;
      float a = 0.f;
      #pragma unroll
      for (int t = 0; t < 4; ++t) {
        const float* Er = Elds + jyr[t] * 128;
        float rrow = wx[xi][0]*Er[jx[xi][0]] + wx[xi][1]*Er[jx[xi][1]]
                   + wx[xi][2]*Er[jx[xi][2]] + wx[xi][3]*Er[jx[xi][3]];
        a = fmaf(wy[t], rrow, a);
      }
      float hm = fmaf(heat[(size_t)bl * 262144 + y * 512 + x], sc, sh);
      float e = a + logf(sp(hm) + 1e-6f);
      if (e > m) {
        float f = expf(m - e);
        S *= f; Sy *= f; Sx *= f; m = e;
      }
      float w = expf(e - m);
      S += w; Sy = fmaf(w, (float)y, Sy); Sx = fmaf(w, (float)x, Sx);
    }
  }
  rm[tid] = m; rS[tid] = S; ry[tid] = Sy; rx[tid] = Sx; __syncthreads();
  for (int o = 128; o > 0; o >>= 1) {
    if (tid < o) {
      float ma = rm[tid], mb = rm[tid + o];
      float M = fmaxf(ma, mb);
      float fa = expf(ma - M), fb = expf(mb - M);
      rS[tid] = rS[tid]*fa + rS[tid+o]*fb;
      ry[tid] = ry[tid]*fa + ry[tid+o]*fb;
      rx[tid] = rx[tid]*fa + rx[tid+o]*fb;
      rm[tid] = M;
    }
    __syncthreads();
  }
  if (tid == 0) {
    float* p = partials + (size_t)blk * 4;
    p[0] = rm[0]; p[1] = rS[0]; p[2] = ry[0]; p[3] = rx[0];
  }
}

__global__ void final_combine_k(const float* __restrict__ partials, float* __restrict__ out) {
  int bl = blockIdx.x;
  if (threadIdx.x != 0) return;
  float M = -1e30f, S = 0.f, Sy = 0.f, Sx = 0.f;
  for (int i = 0; i < 8; ++i) {
    const float* p = partials + (size_t)(bl * 8 + i) * 4;
    float m2 = p[0], s2 = p[1], sy2 = p[2], sx2 = p[3];
    float Mn = fmaxf(M, m2);
    float fa = expf(M - Mn), fb = expf(m2 - Mn);
    S = S*fa + s2*fb; Sy = Sy*fa + sy2*fb; Sx = Sx*fa + sx2*fb; M = Mn;
  }
  out[bl*3 + 0] = 1.f;
  out[bl*3 + 1] = Sy / S;
  out[bl*3 + 2] = Sx / S;
}

extern "C" void kernel_launch(void* const* d_in, const int* in_sizes, int n_in,
                              void* d_out, int out_size, void* d_ws, size_t ws_size,
                              hipStream_t stream) {
  const float* heat  = (const float*)d_in[0];
  const float* cond  = (const float*)d_in[1];
  const float* bias  = (const float*)d_in[2];
  const float* gamma = (const float*)d_in[3];
  const float* beta  = (const float*)d_in[4];
  const int*   vidx  = (const int*)d_in[5];
  float* out = (float*)d_out;
  char* ws = (char*)d_ws;

  float* sums   = (float*)(ws + OFF_SUMS);
  float* params = (float*)(ws + OFF_PARAMS);
  int*   taj = (int*)(ws + OFF_TAJ);   float* taw = (float*)(ws + OFF_TAW);
  int*   tbj = (int*)(ws + OFF_TBJ);   float* tbw = (float*)(ws + OFF_TBW);
  int*   tcj = (int*)(ws + OFF_TCJ);   float* tcw = (float*)(ws + OFF_TCW);
  float* part  = (float*)(ws + OFF_PART);
  float* tmpA  = (float*)(ws + OFF_TMPA);
  float* hmrs  = (float*)(ws + OFF_HMRS);
  unsigned char* pimg = (unsigned char*)(ws + OFF_PIMG);
  float* e_all = (float*)(ws + OFF_EALL);
  float* e128  = (float*)(ws + OFF_E128);

  hipFuncSetAttribute((const void*)conv_mfma_k,
                      hipFuncAttributeMaxDynamicSharedMemorySize, CONV_LDS);

  hipMemsetAsync(sums, 0, 2 * L_ * sizeof(float), stream);
  bn_partial_k<<<L_ * 16, 256, 0, stream>>>(heat, sums);
  tables_k<<<1, 512, 0, stream>>>(taj, taw, tbj, tbw, tcj, tcw, sums, gamma, beta, params);
  down_rows_k<<<74 * 128, 256, 0, stream>>>(heat, params, taj, taw, tmpA);
  down_cols_k<<<74 * 128, 128, 0, stream>>>(tmpA, taj, taw, hmrs);
  prior_rev_k<<<L_ * K_, 256, 0, stream>>>(cond, tbj, tbw, pimg);
  conv_mfma_k<<<2 * L_ * K_, 512, CONV_LDS, stream>>>(hmrs, pimg, bias, vidx, e_all);
  esum_k<<<74, 256, 0, stream>>>(e_all, e128);
  final_partial_k<<<74 * 8, 256, 0, stream>>>(heat, params, e128, tcj, tcw, part);
  final_combine_k<<<74, 64, 0, stream>>>(part, out);
}